// Round 3
// baseline (1937.340 us; speedup 1.0000x reference)
//
#include <hip/hip_runtime.h>
#include <hip/hip_bf16.h>
#include <stdint.h>

#define HORIZON 12

typedef __bf16 bf16x8 __attribute__((ext_vector_type(8)));
typedef float  f32x16 __attribute__((ext_vector_type(16)));

__device__ __forceinline__ unsigned short f2bf(float f) {
  union { float f; uint32_t u; } v; v.f = f;
  return (unsigned short)((v.u + 0x7FFFu + ((v.u >> 16) & 1u)) >> 16);
}

__device__ __forceinline__ void gload16(const void* g, void* l) {
  __builtin_amdgcn_global_load_lds(
      (const __attribute__((address_space(1))) void*)g,
      (__attribute__((address_space(3))) void*)l, 16, 0, 0);
}

__device__ __forceinline__ float sigm(float x) { return 1.0f / (1.0f + __expf(-x)); }
__device__ __forceinline__ float tanh_fast(float x) { return 1.0f - 2.0f / (__expf(2.0f * x) + 1.0f); }

#define MFMA(a, b, c) __builtin_amdgcn_mfma_f32_32x32x16_bf16(a, b, c, 0, 0, 0)

// ---------- prep: cast weights to bf16 in K-major slab layout + bias combos ----------
// Wb layout: matrix m in {Wih0,Whh0,Wih1,Whh1,Wlin} at m*196608; within matrix:
// slab k (K16 window): [rows][16] contiguous -> el = m*196608 + (k*rows + r)*16 + kk.
// Bc: [brz 2x256][bzz 2x256][bin 2x256][bhn 2x256][blin 256] f32.
__global__ void prep(const float* __restrict__ wih, const float* __restrict__ whh,
                     const float* __restrict__ wlin, const float* __restrict__ bih,
                     const float* __restrict__ bhh, const float* __restrict__ blin,
                     unsigned short* __restrict__ Wb, float* __restrict__ Bc) {
  const int stride = gridDim.x * blockDim.x;
  for (int i = blockIdx.x * blockDim.x + threadIdx.x; i < 215296; i += stride) {
    if (i < 212992) {
      const int e = i << 2;
      const float* src; int m, rel;
      if (e < 196608)      { src = wih + e;             m = 0; rel = e; }
      else if (e < 393216) { src = whh + (e - 196608);  m = 1; rel = e - 196608; }
      else if (e < 589824) { src = wih + (e - 196608);  m = 2; rel = e - 393216; }
      else if (e < 786432) { src = whh + (e - 393216);  m = 3; rel = e - 589824; }
      else                 { src = wlin + (e - 786432); m = 4; rel = e - 786432; }
      const int rows = (m < 4) ? 768 : 256;
      const int r = rel >> 8, c = rel & 255;
      const float4 v = *(const float4*)src;
      unsigned short* dst = Wb + m * 196608 + ((c >> 4) * rows + r) * 16 + (c & 15);
      dst[0] = f2bf(v.x); dst[1] = f2bf(v.y); dst[2] = f2bf(v.z); dst[3] = f2bf(v.w);
    } else {
      const int t = i - 212992;
      float v;
      if (t < 512)       { const int l = t >> 8,          d = t & 255; v = bih[l*768+d]     + bhh[l*768+d]; }
      else if (t < 1024) { const int l = (t-512) >> 8,    d = t & 255; v = bih[l*768+256+d] + bhh[l*768+256+d]; }
      else if (t < 1536) { const int l = (t-1024) >> 8,   d = t & 255; v = bih[l*768+512+d]; }
      else if (t < 2048) { const int l = (t-1536) >> 8,   d = t & 255; v = bhh[l*768+512+d]; }
      else               { v = blin[t - 2048]; }
      Bc[t] = v;
    }
  }
}

// ---------- persistent fused decoder ----------
// 256 blocks x 512 threads; block owns batch stripe [b0, b0+64).
// Transposed GEMMs: gates^T[768 x 64] = W[768x256] . x^T ; MFMA 32x32x16:
//   A = W rows (streamed K16 slabs via global_load_lds), B = x/h from LDS,
//   C/D: col = lane&31 = batch, row = (reg&3)+8*(reg>>2)+4*(lane>>5) = dim.
// Wave w owns dims [w*32, w*32+32); h0/h1 fp32 state in C/D-layout registers.
// LDS: XB/H0/H1 bf16 [64][256] (granule^=(row&7) swizzle) + W dbuf 2x24KB + biases.
__global__ __launch_bounds__(512, 2) void rnn_persist(
    const float* __restrict__ y0, const float* __restrict__ h0f,
    const unsigned short* __restrict__ Wb, const float* __restrict__ Bc,
    float* __restrict__ out) {
  extern __shared__ char lds[];
  unsigned short* XB = (unsigned short*)(lds);            // 32768 B
  unsigned short* H0 = (unsigned short*)(lds + 32768);    // 32768 B
  unsigned short* H1 = (unsigned short*)(lds + 65536);    // 32768 B
  char*           WS = lds + 98304;                       // 2 x 24576 B
  float*          BI = (float*)(lds + 147456);            // 9216 B

  const int tid = threadIdx.x;
  const int w   = tid >> 6;
  const int l   = tid & 63;
  const int l31 = l & 31;
  const int hi  = l >> 5;
  const int b0  = blockIdx.x * 64;

  // biases -> LDS
  for (int i = tid; i < 2304; i += 512) BI[i] = Bc[i];

  // x(0) = y0 stripe -> XB (bf16, swizzled)
  for (int q = tid; q < 4096; q += 512) {
    const int row = q >> 6, dq = (q & 63) << 2;
    const float4 v = *(const float4*)(y0 + (size_t)(b0 + row) * 256 + dq);
    ushort4 o; o.x = f2bf(v.x); o.y = f2bf(v.y); o.z = f2bf(v.z); o.w = f2bf(v.w);
    *(ushort4*)((char*)XB + row * 512 + ((((dq >> 3)) ^ (row & 7)) << 4) + ((dq & 7) << 1)) = o;
  }

  // h state: fp32 regs (C/D layout) + bf16 LDS copies
  f32x16 h0s[2], h1s[2];
#pragma unroll
  for (int ct = 0; ct < 2; ++ct) {
    const int brow = ct * 32 + l31;
    const int batch = b0 + brow;
#pragma unroll
    for (int q = 0; q < 4; ++q) {
      const int d0 = w * 32 + q * 8 + hi * 4;
      const float4 a = *(const float4*)(h0f + (size_t)batch * 256 + d0);
      const float4 b = *(const float4*)(h0f + (size_t)(16384 + batch) * 256 + d0);
      h0s[ct][q*4+0] = a.x; h0s[ct][q*4+1] = a.y; h0s[ct][q*4+2] = a.z; h0s[ct][q*4+3] = a.w;
      h1s[ct][q*4+0] = b.x; h1s[ct][q*4+1] = b.y; h1s[ct][q*4+2] = b.z; h1s[ct][q*4+3] = b.w;
      ushort4 o0, o1;
      o0.x = f2bf(a.x); o0.y = f2bf(a.y); o0.z = f2bf(a.z); o0.w = f2bf(a.w);
      o1.x = f2bf(b.x); o1.y = f2bf(b.y); o1.z = f2bf(b.z); o1.w = f2bf(b.w);
      const int g = (w << 2) + q;
      *(ushort4*)((char*)H0 + brow * 512 + ((g ^ (brow & 7)) << 4) + (hi << 3)) = o0;
      *(ushort4*)((char*)H1 + brow * 512 + ((g ^ (brow & 7)) << 4) + (hi << 3)) = o1;
    }
  }

  // stage W slab (sm80 in [0,80), static) into buffer buf; fully coalesced 1KB/issue
  auto stage = [&](int sm80, int buf) {
    const int m = sm80 >> 4, k = sm80 & 15;
    const int rows = (m < 4) ? 768 : 256;
    const size_t sb = ((size_t)m * 196608 + (size_t)(k * rows) * 16) * 2;
    const char* src = (const char*)Wb + sb + (w << 10) + ((size_t)(l ^ ((l >> 3) & 1)) << 4);
    char* dst = WS + buf * 24576 + (w << 10);
    gload16(src, dst);
    if (rows == 768) { gload16(src + 8192, dst + 8192); gload16(src + 16384, dst + 16384); }
  };

  f32x16 Ar[2], Az[2], Ai[2], Ah[2];

  auto zacc = [&](f32x16* A) {
#pragma unroll
    for (int ct = 0; ct < 2; ++ct)
#pragma unroll
      for (int r = 0; r < 16; ++r) A[ct][r] = 0.0f;
  };

  const int halfA = hi ^ ((l31 >> 2) & 1);   // W-slab swizzled half-granule

  // one gi/gh pass: 16 K16 iters; A2 receives the n-gate stream
  auto passG = [&](const unsigned short* Bsrc, f32x16* A0, f32x16* A1, f32x16* A2,
                   int base_sk) {
#pragma unroll
    for (int k = 0; k < 16; ++k) {
      const int par = k & 1;
      int skn = base_sk + k + 1; if (skn >= 80) skn = 0;
      stage(skn, par ^ 1);
      const char* wb = WS + par * 24576;
      const int aoff = (w * 32 + l31) * 32 + halfA * 16;
      const bf16x8 a0 = *(const bf16x8*)(wb + aoff);
      const bf16x8 a1 = *(const bf16x8*)(wb + 8192 + aoff);
      const bf16x8 a2 = *(const bf16x8*)(wb + 16384 + aoff);
      const int g = (k << 1) + hi;
      const bf16x8 b0v = *(const bf16x8*)((const char*)Bsrc + l31 * 512 + ((g ^ (l31 & 7)) << 4));
      const bf16x8 b1v = *(const bf16x8*)((const char*)Bsrc + (32 + l31) * 512 + ((g ^ ((32 + l31) & 7)) << 4));
      A0[0] = MFMA(a0, b0v, A0[0]); A0[1] = MFMA(a0, b1v, A0[1]);
      A1[0] = MFMA(a1, b0v, A1[0]); A1[1] = MFMA(a1, b1v, A1[1]);
      A2[0] = MFMA(a2, b0v, A2[0]); A2[1] = MFMA(a2, b1v, A2[1]);
      __syncthreads();
    }
  };

  // lin pass: slabs 64..79, 256-row slabs, acc in A0
  auto passL = [&](f32x16* A0) {
#pragma unroll
    for (int k = 0; k < 16; ++k) {
      const int par = k & 1;
      int skn = 64 + k + 1; if (skn >= 80) skn = 0;
      stage(skn, par ^ 1);
      const char* wb = WS + par * 24576;
      const bf16x8 a0 = *(const bf16x8*)(wb + (w * 32 + l31) * 32 + halfA * 16);
      const int g = (k << 1) + hi;
      const bf16x8 b0v = *(const bf16x8*)((const char*)H1 + l31 * 512 + ((g ^ (l31 & 7)) << 4));
      const bf16x8 b1v = *(const bf16x8*)((const char*)H1 + (32 + l31) * 512 + ((g ^ ((32 + l31) & 7)) << 4));
      A0[0] = MFMA(a0, b0v, A0[0]); A0[1] = MFMA(a0, b1v, A0[1]);
      __syncthreads();
    }
  };

  // GRU epilogue: gates fp32, update fp32 state, write bf16 to Hlds
  auto epi = [&](int layer, unsigned short* Hlds, f32x16* hs) {
#pragma unroll
    for (int q = 0; q < 4; ++q) {
      const int d0 = layer * 256 + w * 32 + q * 8 + hi * 4;
      const float4 vrz = *(const float4*)&BI[d0];
      const float4 vzz = *(const float4*)&BI[512 + d0];
      const float4 vin = *(const float4*)&BI[1024 + d0];
      const float4 vhn = *(const float4*)&BI[1536 + d0];
      const float brzA[4] = {vrz.x, vrz.y, vrz.z, vrz.w};
      const float bzzA[4] = {vzz.x, vzz.y, vzz.z, vzz.w};
      const float binA[4] = {vin.x, vin.y, vin.z, vin.w};
      const float bhnA[4] = {vhn.x, vhn.y, vhn.z, vhn.w};
      ushort4 o[2];
#pragma unroll
      for (int ct = 0; ct < 2; ++ct) {
#pragma unroll
        for (int r = 0; r < 4; ++r) {
          const int reg = q * 4 + r;
          const float rg = sigm(Ar[ct][reg] + brzA[r]);
          const float zg = sigm(Az[ct][reg] + bzzA[r]);
          const float nn = tanh_fast(Ai[ct][reg] + binA[r] + rg * (Ah[ct][reg] + bhnA[r]));
          const float hv = (1.0f - zg) * nn + zg * hs[ct][reg];
          hs[ct][reg] = hv;
          ((unsigned short*)&o[ct])[r] = f2bf(hv);
        }
      }
#pragma unroll
      for (int ct = 0; ct < 2; ++ct) {
        const int brow = ct * 32 + l31;
        *(ushort4*)((char*)Hlds + brow * 512 + ((((w << 2) + q) ^ (brow & 7)) << 4) + (hi << 3)) = o[ct];
      }
    }
  };

  stage(0, 0);
  __syncthreads();

#pragma unroll 1
  for (int t = 0; t < HORIZON; ++t) {
    // layer 0
    zacc(Ar); zacc(Az); zacc(Ai);
    passG(XB, Ar, Az, Ai, 0);          // gi0: slabs 0..15 (Wih0)
    zacc(Ah);
    passG(H0, Ar, Az, Ah, 16);         // gh0: slabs 16..31 (Whh0)
    epi(0, H0, h0s);
    __syncthreads();
    // layer 1
    zacc(Ar); zacc(Az); zacc(Ai);
    passG(H0, Ar, Az, Ai, 32);         // gi1: input = new h0
    zacc(Ah);
    passG(H1, Ar, Az, Ah, 48);         // gh1
    epi(1, H1, h1s);
    __syncthreads();
    // output linear
    zacc(Ar);
    passL(Ar);
#pragma unroll
    for (int ct = 0; ct < 2; ++ct) {
      const int brow = ct * 32 + l31;
      float* og = out + ((size_t)t * 16384 + b0 + brow) * 256;
#pragma unroll
      for (int q = 0; q < 4; ++q) {
        const int d0 = w * 32 + q * 8 + hi * 4;
        const float4 bl = *(const float4*)&BI[2048 + d0];
        float4 y;
        y.x = Ar[ct][q*4+0] + bl.x;
        y.y = Ar[ct][q*4+1] + bl.y;
        y.z = Ar[ct][q*4+2] + bl.z;
        y.w = Ar[ct][q*4+3] + bl.w;
        *(float4*)(og + d0) = y;
        ushort4 o; o.x = f2bf(y.x); o.y = f2bf(y.y); o.z = f2bf(y.z); o.w = f2bf(y.w);
        *(ushort4*)((char*)XB + brow * 512 + ((((w << 2) + q) ^ (brow & 7)) << 4) + (hi << 3)) = o;
      }
    }
    __syncthreads();
  }
}

// ---------- launch ----------
extern "C" void kernel_launch(void* const* d_in, const int* in_sizes, int n_in,
                              void* d_out, int out_size, void* d_ws, size_t ws_size,
                              hipStream_t stream) {
  (void)in_sizes; (void)n_in; (void)out_size; (void)ws_size;
  const float* y0   = (const float*)d_in[0];
  const float* h0   = (const float*)d_in[1];
  const float* wih  = (const float*)d_in[2];
  const float* whh  = (const float*)d_in[3];
  const float* bih  = (const float*)d_in[4];
  const float* bhh  = (const float*)d_in[5];
  const float* wlin = (const float*)d_in[6];
  const float* blin = (const float*)d_in[7];
  float* out = (float*)d_out;

  unsigned short* Wb = (unsigned short*)d_ws;            // 851968 bf16 els
  float* Bc = (float*)((char*)d_ws + 1703936);           // 2304 f32

  static bool attr_done = false;
  if (!attr_done) {
    hipFuncSetAttribute((const void*)rnn_persist,
                        hipFuncAttributeMaxDynamicSharedMemorySize, 156672);
    attr_done = true;
  }

  prep<<<512, 256, 0, stream>>>(wih, whh, wlin, bih, bhh, blin, Wb, Bc);
  rnn_persist<<<256, 512, 156672, stream>>>(y0, h0, Wb, Bc, out);
}

// Round 4
// 1913.567 us; speedup vs baseline: 1.0124x; 1.0124x over previous
//
#include <hip/hip_runtime.h>
#include <hip/hip_bf16.h>
#include <stdint.h>

#define HORIZON 12

typedef __bf16 bf16x8 __attribute__((ext_vector_type(8)));
typedef float  f32x16 __attribute__((ext_vector_type(16)));

__device__ __forceinline__ unsigned short f2bf(float f) {
  union { float f; uint32_t u; } v; v.f = f;
  return (unsigned short)((v.u + 0x7FFFu + ((v.u >> 16) & 1u)) >> 16);
}

__device__ __forceinline__ float sigm(float x) { return 1.0f / (1.0f + __expf(-x)); }
__device__ __forceinline__ float tanh_fast(float x) { return 1.0f - 2.0f / (__expf(2.0f * x) + 1.0f); }

#define MFMA(a, b, c) __builtin_amdgcn_mfma_f32_32x32x16_bf16(a, b, c, 0, 0, 0)

// ---------- prep: cast weights to bf16 in K-major slab layout + bias combos ----------
// Wb: matrix m in {Wih0,Whh0,Wih1,Whh1,Wlin} at m*196608 els; slab k (K16 window):
// el = m*196608 + (k*rows + r)*16 + kk  (r = output row, kk = k within window).
// Bc: [brz 2x256][bzz 2x256][bin 2x256][bhn 2x256][blin 256] f32.
__global__ void prep(const float* __restrict__ wih, const float* __restrict__ whh,
                     const float* __restrict__ wlin, const float* __restrict__ bih,
                     const float* __restrict__ bhh, const float* __restrict__ blin,
                     unsigned short* __restrict__ Wb, float* __restrict__ Bc) {
  const int stride = gridDim.x * blockDim.x;
  for (int i = blockIdx.x * blockDim.x + threadIdx.x; i < 215296; i += stride) {
    if (i < 212992) {
      const int e = i << 2;
      const float* src; int m, rel;
      if (e < 196608)      { src = wih + e;             m = 0; rel = e; }
      else if (e < 393216) { src = whh + (e - 196608);  m = 1; rel = e - 196608; }
      else if (e < 589824) { src = wih + (e - 196608);  m = 2; rel = e - 393216; }
      else if (e < 786432) { src = whh + (e - 393216);  m = 3; rel = e - 589824; }
      else                 { src = wlin + (e - 786432); m = 4; rel = e - 786432; }
      const int rows = (m < 4) ? 768 : 256;
      const int r = rel >> 8, c = rel & 255;
      const float4 v = *(const float4*)src;
      unsigned short* dst = Wb + m * 196608 + ((c >> 4) * rows + r) * 16 + (c & 15);
      dst[0] = f2bf(v.x); dst[1] = f2bf(v.y); dst[2] = f2bf(v.z); dst[3] = f2bf(v.w);
    } else {
      const int t = i - 212992;
      float v;
      if (t < 512)       { const int l = t >> 8,        d = t & 255; v = bih[l*768+d]     + bhh[l*768+d]; }
      else if (t < 1024) { const int l = (t-512) >> 8,  d = t & 255; v = bih[l*768+256+d] + bhh[l*768+256+d]; }
      else if (t < 1536) { const int l = (t-1024) >> 8, d = t & 255; v = bih[l*768+512+d]; }
      else if (t < 2048) { const int l = (t-1536) >> 8, d = t & 255; v = bhh[l*768+512+d]; }
      else               { v = blin[t - 2048]; }
      Bc[t] = v;
    }
  }
}

// ---------- persistent fused decoder ----------
// 256 blocks x 512 threads; block owns batch stripe [b0, b0+64).
// Orientation: D[row=batch][col=dim]: A = x/h from LDS (batch rows), B = W^T
// fragments streamed from global INTO REGISTERS per wave (wave owns dims
// w*32..w*32+31) -> no cross-wave dependency inside a pass -> no barriers.
// C/D: col = lane&31 = dim, row = (reg&3)+8*(reg>>2)+4*(lane>>5) = batch row.
// LDS x/h: [64 rows][256 dims] bf16, 16B granule g stored at slot g^(row&31)
// (full 5-bit XOR -> even bank load, b128 reads at minimum cycles).
__global__ __launch_bounds__(512, 2) void rnn_persist(
    const float* __restrict__ y0, const float* __restrict__ h0f,
    const unsigned short* __restrict__ Wb, const float* __restrict__ Bc,
    float* __restrict__ out) {
  extern __shared__ char lds[];
  char* XB = lds;            // 32 KB bf16 [64][256]
  char* H0 = lds + 32768;    // 32 KB
  char* H1 = lds + 65536;    // 32 KB
  char* SC = lds + 98304;    // 32 KB f32 [32][256] transpose scratch

  const int tid = threadIdx.x;
  const int w   = tid >> 6;
  const int l   = tid & 63;
  const int l31 = l & 31;
  const int hi  = l >> 5;
  const int b0  = blockIdx.x * 64;
  const int dw  = w * 32 + l31;          // this lane's output dim
  const int sub2 = (l31 & 7) * 2;        // byte pos of dim within its granule
  const int gdw  = w * 4 + (l31 >> 3);   // dim-granule index of dw

  f32x16 Ar[2], Az[2], Ai[2], Ah[2], h0s[2], h1s[2];

  // ---- init XB = bf16(y0 stripe), swizzled ----
#pragma unroll
  for (int rr = 0; rr < 8; ++rr) {
    const int idx = rr * 2048 + tid * 4;
    const int row = idx >> 8, dd = idx & 255;
    const float4 v = *(const float4*)(y0 + (size_t)(b0 + row) * 256 + dd);
    ushort4 o; o.x = f2bf(v.x); o.y = f2bf(v.y); o.z = f2bf(v.z); o.w = f2bf(v.w);
    *(ushort4*)(XB + row * 512 + (((dd >> 3) ^ (row & 31)) << 4) + (dd & 7) * 2) = o;
  }

  // ---- init h state: coalesced coop read -> SC -> per-lane gather ----
  auto initH = [&](const float* src, f32x16 (&hs)[2], char* Hl) {
#pragma unroll
    for (int ct = 0; ct < 2; ++ct) {
      __syncthreads();
#pragma unroll
      for (int rr = 0; rr < 4; ++rr) {
        const int idx = rr * 2048 + tid * 4;
        const int row = idx >> 8, dd = idx & 255;
        *(float4*)(SC + row * 1024 + dd * 4) =
            *(const float4*)(src + (size_t)(b0 + ct * 32 + row) * 256 + dd);
      }
      __syncthreads();
#pragma unroll
      for (int reg = 0; reg < 16; ++reg) {
        const int rl = (reg & 3) + 8 * (reg >> 2) + 4 * hi;
        const float v = *(const float*)(SC + rl * 1024 + dw * 4);
        hs[ct][reg] = v;
        *(unsigned short*)(Hl + (ct * 32 + rl) * 512 + ((gdw ^ rl) << 4) + sub2) = f2bf(v);
      }
    }
  };
  initH(h0f, h0s, H0);
  initH(h0f + (size_t)16384 * 256, h1s, H1);
  __syncthreads();

  const char* Wp = (const char*)Wb;

  auto zacc = [&](f32x16 (&A)[2]) {
#pragma unroll
    for (int ct = 0; ct < 2; ++ct)
#pragma unroll
      for (int r = 0; r < 16; ++r) A[ct][r] = 0.0f;
  };

  // fused gi+gh pass: 16 K16 iters, 6 reg-streamed W frags, 12 MFMA/iter
  auto passGRU = [&](const char* Xs, const char* Hs, size_t mI, size_t mH) {
    const char* bI0 = Wp + mI + (size_t)(0 * 256 + dw) * 32 + hi * 16;
    const char* bI1 = Wp + mI + (size_t)(1 * 256 + dw) * 32 + hi * 16;
    const char* bI2 = Wp + mI + (size_t)(2 * 256 + dw) * 32 + hi * 16;
    const char* bH0 = Wp + mH + (size_t)(0 * 256 + dw) * 32 + hi * 16;
    const char* bH1 = Wp + mH + (size_t)(1 * 256 + dw) * 32 + hi * 16;
    const char* bH2 = Wp + mH + (size_t)(2 * 256 + dw) * 32 + hi * 16;
    bf16x8 c0 = *(const bf16x8*)bI0, c1 = *(const bf16x8*)bI1, c2 = *(const bf16x8*)bI2;
    bf16x8 c3 = *(const bf16x8*)bH0, c4 = *(const bf16x8*)bH1, c5 = *(const bf16x8*)bH2;
#pragma unroll
    for (int k = 0; k < 16; ++k) {
      const int o = (k < 15) ? (k + 1) * 24576 : 0;   // slab stride = 768*32 B
      const bf16x8 n0 = *(const bf16x8*)(bI0 + o);
      const bf16x8 n1 = *(const bf16x8*)(bI1 + o);
      const bf16x8 n2 = *(const bf16x8*)(bI2 + o);
      const bf16x8 n3 = *(const bf16x8*)(bH0 + o);
      const bf16x8 n4 = *(const bf16x8*)(bH1 + o);
      const bf16x8 n5 = *(const bf16x8*)(bH2 + o);
      const int go = ((2 * k + hi) ^ l31) << 4;
      bf16x8 aX[2], aH[2];
#pragma unroll
      for (int ct = 0; ct < 2; ++ct) {
        aX[ct] = *(const bf16x8*)(Xs + (ct * 32 + l31) * 512 + go);
        aH[ct] = *(const bf16x8*)(Hs + (ct * 32 + l31) * 512 + go);
      }
#pragma unroll
      for (int ct = 0; ct < 2; ++ct) {
        Ar[ct] = MFMA(aX[ct], c0, Ar[ct]);
        Az[ct] = MFMA(aX[ct], c1, Az[ct]);
        Ai[ct] = MFMA(aX[ct], c2, Ai[ct]);
        Ar[ct] = MFMA(aH[ct], c3, Ar[ct]);
        Az[ct] = MFMA(aH[ct], c4, Az[ct]);
        Ah[ct] = MFMA(aH[ct], c5, Ah[ct]);
      }
      c0 = n0; c1 = n1; c2 = n2; c3 = n3; c4 = n4; c5 = n5;
    }
  };

  auto passLin = [&](const char* Hs, size_t mL) {
    const char* bL = Wp + mL + (size_t)dw * 32 + hi * 16;
    bf16x8 c = *(const bf16x8*)bL;
#pragma unroll
    for (int k = 0; k < 16; ++k) {
      const int o = (k < 15) ? (k + 1) * 8192 : 0;    // slab stride = 256*32 B
      const bf16x8 n = *(const bf16x8*)(bL + o);
      const int go = ((2 * k + hi) ^ l31) << 4;
      const bf16x8 a0 = *(const bf16x8*)(Hs + l31 * 512 + go);
      const bf16x8 a1 = *(const bf16x8*)(Hs + (32 + l31) * 512 + go);
      Ar[0] = MFMA(a0, c, Ar[0]);
      Ar[1] = MFMA(a1, c, Ar[1]);
      c = n;
    }
  };

  auto epi = [&](int L, char* Hl, f32x16 (&hs)[2]) {
    const float brz = Bc[L * 256 + dw];
    const float bzz = Bc[512 + L * 256 + dw];
    const float bin = Bc[1024 + L * 256 + dw];
    const float bhn = Bc[1536 + L * 256 + dw];
#pragma unroll
    for (int ct = 0; ct < 2; ++ct) {
#pragma unroll
      for (int reg = 0; reg < 16; ++reg) {
        const float rg = sigm(Ar[ct][reg] + brz);
        const float zg = sigm(Az[ct][reg] + bzz);
        const float nn = tanh_fast(Ai[ct][reg] + bin + rg * (Ah[ct][reg] + bhn));
        const float hv = (1.0f - zg) * nn + zg * hs[ct][reg];
        hs[ct][reg] = hv;
        const int rl = (reg & 3) + 8 * (reg >> 2) + 4 * hi;
        *(unsigned short*)(Hl + (ct * 32 + rl) * 512 + ((gdw ^ rl) << 4) + sub2) = f2bf(hv);
      }
    }
  };

#pragma unroll 1
  for (int t = 0; t < HORIZON; ++t) {
    // layer 0: gi(XB) + gh(H0-old) fused
    zacc(Ar); zacc(Az); zacc(Ai); zacc(Ah);
    passGRU(XB, H0, 0, 393216);
    __syncthreads();            // all pass reads of H0-old done
    epi(0, H0, h0s);
    __syncthreads();            // H0-new visible
    // layer 1: gi(H0-new) + gh(H1-old)
    zacc(Ar); zacc(Az); zacc(Ai); zacc(Ah);
    passGRU(H0, H1, 786432, 1179648);
    __syncthreads();
    epi(1, H1, h1s);
    __syncthreads();
    // output linear
    zacc(Ar);
    passLin(H1, 1572864);
    const float bl = Bc[2048 + dw];
#pragma unroll
    for (int ct = 0; ct < 2; ++ct) {
      // scatter fp32 y (reg layout) -> SC
#pragma unroll
      for (int reg = 0; reg < 16; ++reg) {
        const int rl = (reg & 3) + 8 * (reg >> 2) + 4 * hi;
        *(float*)(SC + rl * 1024 + dw * 4) = Ar[ct][reg] + bl;
      }
      __syncthreads();
      // cooperative coalesced store + bf16 next-x write
      float* og = out + ((size_t)t * 16384 + b0 + ct * 32) * 256;
#pragma unroll
      for (int rr = 0; rr < 4; ++rr) {
        const int idx = rr * 2048 + tid * 4;
        const int row = idx >> 8, dd = idx & 255;
        const float4 v = *(const float4*)(SC + row * 1024 + dd * 4);
        *(float4*)(og + row * 256 + dd) = v;
        ushort4 o; o.x = f2bf(v.x); o.y = f2bf(v.y); o.z = f2bf(v.z); o.w = f2bf(v.w);
        const int xr = ct * 32 + row;
        *(ushort4*)(XB + xr * 512 + (((dd >> 3) ^ (xr & 31)) << 4) + (dd & 7) * 2) = o;
      }
      __syncthreads();
    }
  }
}

// ---------- launch ----------
extern "C" void kernel_launch(void* const* d_in, const int* in_sizes, int n_in,
                              void* d_out, int out_size, void* d_ws, size_t ws_size,
                              hipStream_t stream) {
  (void)in_sizes; (void)n_in; (void)out_size; (void)ws_size;
  const float* y0   = (const float*)d_in[0];
  const float* h0   = (const float*)d_in[1];
  const float* wih  = (const float*)d_in[2];
  const float* whh  = (const float*)d_in[3];
  const float* bih  = (const float*)d_in[4];
  const float* bhh  = (const float*)d_in[5];
  const float* wlin = (const float*)d_in[6];
  const float* blin = (const float*)d_in[7];
  float* out = (float*)d_out;

  unsigned short* Wb = (unsigned short*)d_ws;            // 851968 bf16 els
  float* Bc = (float*)((char*)d_ws + 1703936);           // 2304 f32

  static bool attr_done = false;
  if (!attr_done) {
    hipFuncSetAttribute((const void*)rnn_persist,
                        hipFuncAttributeMaxDynamicSharedMemorySize, 131072);
    attr_done = true;
  }

  prep<<<512, 256, 0, stream>>>(wih, whh, wlin, bih, bhh, blin, Wb, Bc);
  rnn_persist<<<256, 512, 131072, stream>>>(y0, h0, Wb, Bc, out);
}

// Round 5
// 562.991 us; speedup vs baseline: 3.4412x; 3.3989x over previous
//
#include <hip/hip_runtime.h>
#include <hip/hip_bf16.h>
#include <stdint.h>

#define HORIZON 12

typedef __bf16 bf16x8 __attribute__((ext_vector_type(8)));
typedef float  f32x16 __attribute__((ext_vector_type(16)));

__device__ __forceinline__ unsigned short f2bf(float f) {
  union { float f; uint32_t u; } v; v.f = f;
  return (unsigned short)((v.u + 0x7FFFu + ((v.u >> 16) & 1u)) >> 16);
}
__device__ __forceinline__ float bf2f(unsigned short s) {
  union { uint32_t u; float f; } v; v.u = ((uint32_t)s) << 16;
  return v.f;
}

__device__ __forceinline__ float sigm(float x) { return 1.0f / (1.0f + __expf(-x)); }
__device__ __forceinline__ float tanh_fast(float x) { return 1.0f - 2.0f / (__expf(2.0f * x) + 1.0f); }

#define MFMA(a, b, c) __builtin_amdgcn_mfma_f32_32x32x16_bf16(a, b, c, 0, 0, 0)

// ---------- prep: cast weights to bf16 in K-major slab layout + bias combos ----------
// Wb: matrix m in {Wih0,Whh0,Wih1,Whh1,Wlin} at m*196608 els; slab k (K16 window):
// el = m*196608 + (k*rows + r)*16 + kk  (r = output row, kk = k within window).
// Bc: [brz 2x256][bzz 2x256][bin 2x256][bhn 2x256][blin 256] f32.
__global__ void prep(const float* __restrict__ wih, const float* __restrict__ whh,
                     const float* __restrict__ wlin, const float* __restrict__ bih,
                     const float* __restrict__ bhh, const float* __restrict__ blin,
                     unsigned short* __restrict__ Wb, float* __restrict__ Bc) {
  const int stride = gridDim.x * blockDim.x;
  for (int i = blockIdx.x * blockDim.x + threadIdx.x; i < 215296; i += stride) {
    if (i < 212992) {
      const int e = i << 2;
      const float* src; int m, rel;
      if (e < 196608)      { src = wih + e;             m = 0; rel = e; }
      else if (e < 393216) { src = whh + (e - 196608);  m = 1; rel = e - 196608; }
      else if (e < 589824) { src = wih + (e - 196608);  m = 2; rel = e - 393216; }
      else if (e < 786432) { src = whh + (e - 393216);  m = 3; rel = e - 589824; }
      else                 { src = wlin + (e - 786432); m = 4; rel = e - 786432; }
      const int rows = (m < 4) ? 768 : 256;
      const int r = rel >> 8, c = rel & 255;
      const float4 v = *(const float4*)src;
      unsigned short* dst = Wb + m * 196608 + ((c >> 4) * rows + r) * 16 + (c & 15);
      dst[0] = f2bf(v.x); dst[1] = f2bf(v.y); dst[2] = f2bf(v.z); dst[3] = f2bf(v.w);
    } else {
      const int t = i - 212992;
      float v;
      if (t < 512)       { const int l = t >> 8,        d = t & 255; v = bih[l*768+d]     + bhh[l*768+d]; }
      else if (t < 1024) { const int l = (t-512) >> 8,  d = t & 255; v = bih[l*768+256+d] + bhh[l*768+256+d]; }
      else if (t < 1536) { const int l = (t-1024) >> 8, d = t & 255; v = bih[l*768+512+d]; }
      else if (t < 2048) { const int l = (t-1536) >> 8, d = t & 255; v = bhh[l*768+512+d]; }
      else               { v = blin[t - 2048]; }
      Bc[t] = v;
    }
  }
}

// ---------- persistent fused decoder ----------
// 256 blocks x 512 threads; block owns batch stripe [b0, b0+64).
// D[row=batch][col=dim]: A = x/h bf16 from LDS (batch rows), B = W^T fragments
// streamed from global INTO REGISTERS per wave (wave owns dims w*32..+31) ->
// no cross-wave dependency inside a pass -> no barriers inside passes.
// C/D: col = lane&31 = dim, row = (reg&3)+8*(reg>>2)+4*(lane>>5) = batch row.
// h state lives ONLY as bf16 in LDS (owner-exclusive RMW in epilogue) ->
// live VGPRs ~212 (acc 128 + 12 W-frags 48 + A-frags 16 + addr) -> no spills.
// LDS x/h: [64 rows][256 dims] bf16, granule g at slot g^(row&31) (conflict-free).
__global__ __launch_bounds__(512) __attribute__((amdgpu_waves_per_eu(2, 2)))
void rnn_persist(
    const float* __restrict__ y0, const float* __restrict__ h0f,
    const unsigned short* __restrict__ Wb, const float* __restrict__ Bc,
    float* __restrict__ out) {
  extern __shared__ char lds[];
  char* XB = lds;            // 32 KB bf16 [64][256]
  char* H0 = lds + 32768;    // 32 KB
  char* H1 = lds + 65536;    // 32 KB
  char* SC = lds + 98304;    // 32 KB f32 [32][256] transpose scratch

  const int tid = threadIdx.x;
  const int w   = tid >> 6;
  const int l   = tid & 63;
  const int l31 = l & 31;
  const int hi  = l >> 5;
  const int b0  = blockIdx.x * 64;
  const int dw  = w * 32 + l31;          // this lane's output dim
  const int sub2 = (l31 & 7) * 2;        // byte pos of dim within its granule
  const int gdw  = w * 4 + (l31 >> 3);   // dim-granule index of dw

  f32x16 Ar[2], Az[2], Ai[2], Ah[2];

  // ---- init XB = bf16(y0 stripe), swizzled ----
#pragma unroll
  for (int rr = 0; rr < 8; ++rr) {
    const int idx = rr * 2048 + tid * 4;
    const int row = idx >> 8, dd = idx & 255;
    const float4 v = *(const float4*)(y0 + (size_t)(b0 + row) * 256 + dd);
    ushort4 o; o.x = f2bf(v.x); o.y = f2bf(v.y); o.z = f2bf(v.z); o.w = f2bf(v.w);
    *(ushort4*)(XB + row * 512 + (((dd >> 3) ^ (row & 31)) << 4) + (dd & 7) * 2) = o;
  }

  // ---- init H0/H1 = bf16(h0 stripes), swizzled (h carried in bf16 LDS only) ----
  auto initH = [&](const float* src, char* Hl) {
#pragma unroll
    for (int rr = 0; rr < 8; ++rr) {
      const int idx = rr * 2048 + tid * 4;
      const int row = idx >> 8, dd = idx & 255;
      const float4 v = *(const float4*)(src + (size_t)(b0 + row) * 256 + dd);
      ushort4 o; o.x = f2bf(v.x); o.y = f2bf(v.y); o.z = f2bf(v.z); o.w = f2bf(v.w);
      *(ushort4*)(Hl + row * 512 + (((dd >> 3) ^ (row & 31)) << 4) + (dd & 7) * 2) = o;
    }
  };
  initH(h0f, H0);
  initH(h0f + (size_t)16384 * 256, H1);
  __syncthreads();

  const char* Wp = (const char*)Wb;

  auto zacc = [&](f32x16 (&A)[2]) {
#pragma unroll
    for (int ct = 0; ct < 2; ++ct)
#pragma unroll
      for (int r = 0; r < 16; ++r) A[ct][r] = 0.0f;
  };

  // fused gi+gh pass: 16 K16 iters, 6 reg-streamed W frags, 12 MFMA/iter
  auto passGRU = [&](const char* Xs, const char* Hs, size_t mI, size_t mH) {
    const char* bI0 = Wp + mI + (size_t)(0 * 256 + dw) * 32 + hi * 16;
    const char* bI1 = Wp + mI + (size_t)(1 * 256 + dw) * 32 + hi * 16;
    const char* bI2 = Wp + mI + (size_t)(2 * 256 + dw) * 32 + hi * 16;
    const char* bH0 = Wp + mH + (size_t)(0 * 256 + dw) * 32 + hi * 16;
    const char* bH1 = Wp + mH + (size_t)(1 * 256 + dw) * 32 + hi * 16;
    const char* bH2 = Wp + mH + (size_t)(2 * 256 + dw) * 32 + hi * 16;
    bf16x8 c0 = *(const bf16x8*)bI0, c1 = *(const bf16x8*)bI1, c2 = *(const bf16x8*)bI2;
    bf16x8 c3 = *(const bf16x8*)bH0, c4 = *(const bf16x8*)bH1, c5 = *(const bf16x8*)bH2;
#pragma unroll 4
    for (int k = 0; k < 16; ++k) {
      const int o = (k < 15) ? (k + 1) * 24576 : 0;   // slab stride = 768*32 B
      const bf16x8 n0 = *(const bf16x8*)(bI0 + o);
      const bf16x8 n1 = *(const bf16x8*)(bI1 + o);
      const bf16x8 n2 = *(const bf16x8*)(bI2 + o);
      const bf16x8 n3 = *(const bf16x8*)(bH0 + o);
      const bf16x8 n4 = *(const bf16x8*)(bH1 + o);
      const bf16x8 n5 = *(const bf16x8*)(bH2 + o);
      const int go = ((2 * k + hi) ^ l31) << 4;
      bf16x8 aX[2], aH[2];
#pragma unroll
      for (int ct = 0; ct < 2; ++ct) {
        aX[ct] = *(const bf16x8*)(Xs + (ct * 32 + l31) * 512 + go);
        aH[ct] = *(const bf16x8*)(Hs + (ct * 32 + l31) * 512 + go);
      }
#pragma unroll
      for (int ct = 0; ct < 2; ++ct) {
        Ar[ct] = MFMA(aX[ct], c0, Ar[ct]);
        Az[ct] = MFMA(aX[ct], c1, Az[ct]);
        Ai[ct] = MFMA(aX[ct], c2, Ai[ct]);
        Ar[ct] = MFMA(aH[ct], c3, Ar[ct]);
        Az[ct] = MFMA(aH[ct], c4, Az[ct]);
        Ah[ct] = MFMA(aH[ct], c5, Ah[ct]);
      }
      c0 = n0; c1 = n1; c2 = n2; c3 = n3; c4 = n4; c5 = n5;
    }
  };

  auto passLin = [&](const char* Hs, size_t mL) {
    const char* bL = Wp + mL + (size_t)dw * 32 + hi * 16;
    bf16x8 c = *(const bf16x8*)bL;
#pragma unroll 4
    for (int k = 0; k < 16; ++k) {
      const int o = (k < 15) ? (k + 1) * 8192 : 0;    // slab stride = 256*32 B
      const bf16x8 n = *(const bf16x8*)(bL + o);
      const int go = ((2 * k + hi) ^ l31) << 4;
      const bf16x8 a0 = *(const bf16x8*)(Hs + l31 * 512 + go);
      const bf16x8 a1 = *(const bf16x8*)(Hs + (32 + l31) * 512 + go);
      Ar[0] = MFMA(a0, c, Ar[0]);
      Ar[1] = MFMA(a1, c, Ar[1]);
      c = n;
    }
  };

  // GRU epilogue: owner-exclusive bf16 RMW of h in LDS, gates in fp32
  auto epi = [&](int L, char* Hl) {
    const float brz = Bc[L * 256 + dw];
    const float bzz = Bc[512 + L * 256 + dw];
    const float bin = Bc[1024 + L * 256 + dw];
    const float bhn = Bc[1536 + L * 256 + dw];
#pragma unroll
    for (int ct = 0; ct < 2; ++ct) {
#pragma unroll
      for (int reg = 0; reg < 16; ++reg) {
        const int rl = (reg & 3) + 8 * (reg >> 2) + 4 * hi;
        unsigned short* hp =
            (unsigned short*)(Hl + (ct * 32 + rl) * 512 + ((gdw ^ rl) << 4) + sub2);
        const float hold = bf2f(*hp);
        const float rg = sigm(Ar[ct][reg] + brz);
        const float zg = sigm(Az[ct][reg] + bzz);
        const float nn = tanh_fast(Ai[ct][reg] + bin + rg * (Ah[ct][reg] + bhn));
        const float hv = (1.0f - zg) * nn + zg * hold;
        *hp = f2bf(hv);
      }
    }
  };

#pragma unroll 1
  for (int t = 0; t < HORIZON; ++t) {
    // layer 0: gi(XB) + gh(H0-old) fused
    zacc(Ar); zacc(Az); zacc(Ai); zacc(Ah);
    passGRU(XB, H0, 0, 393216);
    __syncthreads();            // all pass reads of H0-old done
    epi(0, H0);
    __syncthreads();            // H0-new visible
    // layer 1: gi(H0-new) + gh(H1-old)
    zacc(Ar); zacc(Az); zacc(Ai); zacc(Ah);
    passGRU(H0, H1, 786432, 1179648);
    __syncthreads();
    epi(1, H1);
    __syncthreads();
    // output linear
    zacc(Ar);
    passLin(H1, 1572864);
    const float bl = Bc[2048 + dw];
#pragma unroll
    for (int ct = 0; ct < 2; ++ct) {
      // scatter fp32 y (reg layout) -> SC
#pragma unroll
      for (int reg = 0; reg < 16; ++reg) {
        const int rl = (reg & 3) + 8 * (reg >> 2) + 4 * hi;
        *(float*)(SC + rl * 1024 + dw * 4) = Ar[ct][reg] + bl;
      }
      __syncthreads();
      // cooperative coalesced store + bf16 next-x write
      float* og = out + ((size_t)t * 16384 + b0 + ct * 32) * 256;
#pragma unroll
      for (int rr = 0; rr < 4; ++rr) {
        const int idx = rr * 2048 + tid * 4;
        const int row = idx >> 8, dd = idx & 255;
        const float4 v = *(const float4*)(SC + row * 1024 + dd * 4);
        *(float4*)(og + row * 256 + dd) = v;
        ushort4 o; o.x = f2bf(v.x); o.y = f2bf(v.y); o.z = f2bf(v.z); o.w = f2bf(v.w);
        const int xr = ct * 32 + row;
        *(ushort4*)(XB + xr * 512 + (((dd >> 3) ^ (xr & 31)) << 4) + (dd & 7) * 2) = o;
      }
      __syncthreads();
    }
  }
}

// ---------- launch ----------
extern "C" void kernel_launch(void* const* d_in, const int* in_sizes, int n_in,
                              void* d_out, int out_size, void* d_ws, size_t ws_size,
                              hipStream_t stream) {
  (void)in_sizes; (void)n_in; (void)out_size; (void)ws_size;
  const float* y0   = (const float*)d_in[0];
  const float* h0   = (const float*)d_in[1];
  const float* wih  = (const float*)d_in[2];
  const float* whh  = (const float*)d_in[3];
  const float* bih  = (const float*)d_in[4];
  const float* bhh  = (const float*)d_in[5];
  const float* wlin = (const float*)d_in[6];
  const float* blin = (const float*)d_in[7];
  float* out = (float*)d_out;

  unsigned short* Wb = (unsigned short*)d_ws;            // 851968 bf16 els
  float* Bc = (float*)((char*)d_ws + 1703936);           // 2304 f32

  static bool attr_done = false;
  if (!attr_done) {
    hipFuncSetAttribute((const void*)rnn_persist,
                        hipFuncAttributeMaxDynamicSharedMemorySize, 131072);
    attr_done = true;
  }

  prep<<<512, 256, 0, stream>>>(wih, whh, wlin, bih, bhh, blin, Wb, Bc);
  rnn_persist<<<256, 512, 131072, stream>>>(y0, h0, Wb, Bc, out);
}